// Round 6
// baseline (16804.128 us; speedup 1.0000x reference)
//
#include <hip/hip_runtime.h>
#include <hip/hip_bf16.h>

// ---------------- sizes ----------------
#define H    400
#define SEG  416          // per-layer feature segment, padded to 13*32
#define G4   1600
#define TT   1024
#define BB   64
#define NOUT 121
#define KS0  13
#define KS12 26
#define FPAD 1248         // 3*SEG
#define KSL  39
#define NWG  13           // WGs per layer (flag slots per line)

typedef __attribute__((ext_vector_type(8))) short bf16x8;
typedef __attribute__((ext_vector_type(4))) float f32x4;
typedef unsigned short u16;

// ---------------- persistent device state ----------------
__device__ __align__(16) u16   g_outs[BB * TT][FPAD];   // inter-layer + final GEMM A
__device__ __align__(16) u16   g_h[3][2][BB][SEG];      // self h, parity double buffer
__device__ __align__(16) u16   g_pk0[100][KS0][512];
__device__ __align__(16) u16   g_pk1[100][KS12][512];
__device__ __align__(16) u16   g_pk2[100][KS12][512];
__device__ __align__(16) u16   g_pkl[8][KSL][512];
__device__ float g_bsum[3][G4];
__device__ float g_wx[3][G4][3];
__device__ float g_bl[128];
// one flag line per layer: slot w2 = t+1 when WG (l,w2) finished step t
__device__ __align__(128) int g_fl[3][32];
__device__ int   g_abort;

// ---------------- helpers ----------------
__device__ inline u16 f2b(float f) {
  union { float f; unsigned u; } v; v.f = f;
  unsigned r = v.u + 0x7FFF + ((v.u >> 16) & 1);
  return (u16)(r >> 16);
}
__device__ inline float sigm(float x) { return 1.f / (1.f + __expf(-x)); }
__device__ inline float tanh_(float x) { return 2.f * sigm(2.f * x) - 1.f; }

// verified cross-XCD coherent accessors: sc0 sc1 only
__device__ inline void st16_s(u16* p, unsigned v) {
  asm volatile("global_store_short %0, %1, off sc0 sc1" :: "v"(p), "v"(v) : "memory");
}
__device__ inline void st32_s(int* p, int v) {
  asm volatile("global_store_dword %0, %1, off sc0 sc1" :: "v"(p), "v"(v) : "memory");
}
__device__ inline int poll_s(const int* p) {
  int v;
  asm volatile("global_load_dword %0, %1, off sc0 sc1\n\ts_waitcnt vmcnt(0)"
               : "=v"(v) : "v"(p) : "memory");
  return v;
}
// wave-cooperative wait: all NWG slots >= tv (slot==skip exempt). 1 = abort.
__device__ inline int wait_line(const int* line, int tv, int skip) {
  const int slot = threadIdx.x & 31;
  const int* p = line + slot;
  const bool act = (slot < NWG) && (slot != skip);
  long n = 0;
  for (;;) {
    int v = poll_s(p);
    if (__all((!act) || (v >= tv))) return 0;
    if ((++n & 255) == 0) {
      if (poll_s(&g_abort)) return 1;
      if (n > (1L << 21)) { st32_s(&g_abort, 1); return 1; }
    }
  }
}

// ---------------- setup kernels ----------------
__global__ void k_zero() {
  int i = blockIdx.x * blockDim.x + threadIdx.x;
  if (i == 0) g_abort = 0;
  if (i < 3 * 32) (&g_fl[0][0])[i] = 0;
  if (i < 3 * 2 * BB * SEG / 2) ((unsigned*)g_h)[i] = 0u;
  if (i < BB * TT * 24) {                  // zero pad columns of g_outs
    int r = i / 24, j = i % 24;
    int seg = j >> 3, w = j & 7;
    *(unsigned*)&g_outs[r][seg * SEG + 400 + w * 2] = 0u;
  }
}

__global__ void k_pack_rec(const float* Wih, const float* Whh, int layer,
                           int ksteps, int kin) {
  int i = blockIdx.x * blockDim.x + threadIdx.x;
  int total = 100 * ksteps * 512;
  if (i >= total) return;
  int j = i & 7, lane = (i >> 3) & 63;
  int ks = (i >> 9) % ksteps, nt = (i >> 9) / ksteps;
  int g = nt / 25, jt = nt % 25;
  int n  = g * 400 + jt * 16 + (lane & 15);
  int kk = (lane >> 4) * 8 + j;
  float v = 0.f;
  if (layer == 0) {
    int k = ks * 32 + kk;
    if (k < H) v = Whh[n * H + k];
  } else {
    if (ks < KS0) { int k = ks * 32 + kk;         if (k < H) v = Wih[n * kin + 3 + k]; }
    else          { int k = (ks - KS0) * 32 + kk; if (k < H) v = Whh[n * H + k]; }
  }
  u16* dst = (layer == 0) ? &g_pk0[0][0][0] : (layer == 1 ? &g_pk1[0][0][0] : &g_pk2[0][0][0]);
  dst[i] = f2b(v);
}

__global__ void k_pack_wl(const float* Wl, const float* bl) {
  int i = blockIdx.x * blockDim.x + threadIdx.x;
  if (i < 128) g_bl[i] = (i < NOUT) ? bl[i] : 0.f;
  int total = 8 * KSL * 512;
  if (i >= total) return;
  int j = i & 7, lane = (i >> 3) & 63;
  int ks = (i >> 9) % KSL, nt = (i >> 9) / KSL;
  int n = nt * 16 + (lane & 15);
  int k = ks * 32 + (lane >> 4) * 8 + j;
  int seg = k / SEG, jj = k - seg * SEG;
  float v = 0.f;
  if (n < NOUT && jj < 400) v = Wl[n * 1200 + seg * 400 + jj];
  (&g_pkl[0][0][0])[i] = f2b(v);
}

__global__ void k_pack_misc(const float* Wih0, const float* bih0, const float* bhh0,
                            const float* Wih1, const float* bih1, const float* bhh1,
                            const float* Wih2, const float* bih2, const float* bhh2) {
  int i = blockIdx.x * blockDim.x + threadIdx.x;
  if (i >= 3 * G4) return;
  int l = i / G4, n = i % G4;
  const float* bi = l == 0 ? bih0 : (l == 1 ? bih1 : bih2);
  const float* bh = l == 0 ? bhh0 : (l == 1 ? bhh1 : bhh2);
  const float* wi = l == 0 ? Wih0 : (l == 1 ? Wih1 : Wih2);
  int kin = l == 0 ? 3 : 403;
  g_bsum[l][n] = bi[n] + bh[n];
  for (int c = 0; c < 3; ++c) g_wx[l][n][c] = wi[n * kin + c];
}

// ---------------- persistent fat-wave LSTM ----------------
// 39 WGs = 3 layers x 13 WGs. WG (l,w2) owns cols [w2*32, w2*32+32) (WG12: 16).
// Waves: (jts = wv&1, kh = wv>>1). Wave holds weights for its 16-col jt tile x
// K-half kh, computes ALL 4 mtiles (A 2-deep pipelined), split-K join via LDS,
// epilogues mtiles {kh*2, kh*2+1}. One flag line per layer (13 slots, per-WG).
__global__ __launch_bounds__(256, 1) void k_lstm(const float* __restrict__ X) {
  const int wg = blockIdx.x;
  const int l = wg / NWG, w2 = wg % NWG;
  const int tid = threadIdx.x;
  const int lane = tid & 63;
  const int wv = tid >> 6;
  const int brow = lane & 15;
  const int kg = lane >> 4;
  const int jts = wv & 1, kh = wv >> 1;
  const int jt = w2 * 2 + jts;
  const bool idle = (jt >= 25);
  const int jh = jt * 16 + brow;

  const bool selfw = (l == 0) || (kh == 1);
  const int nk   = (l == 0) ? (kh ? 6 : 7) : 13;       // k-steps this wave
  const int ksA0 = (l == 0 && kh) ? 7 : 0;             // A chunk start in source row
  const int wks0 = (l == 0) ? ksA0 : kh * 13;          // weight ks start
  const int nks  = (l == 0) ? KS0 : KS12;
  const u16* pk = (l == 0) ? &g_pk0[0][0][0] : (l == 1 ? &g_pk1[0][0][0] : &g_pk2[0][0][0]);

  bf16x8 Bf[4][13];
  if (!idle) {
#pragma unroll
    for (int g = 0; g < 4; ++g)
#pragma unroll
      for (int j = 0; j < 13; ++j)
        if (j < nk)
          Bf[g][j] = *(const bf16x8*)&pk[(((g * 25 + jt) * nks + wks0 + j) * 64 + lane) * 8];
  }

  const int am0 = kh * 2;                 // epilogue-owned mtiles am0, am0+1
  float bsum[4], wxc[4][3];
  if (!idle) {
#pragma unroll
    for (int g = 0; g < 4; ++g) {
      int n = g * 400 + jh;
      bsum[g] = g_bsum[l][n];
      wxc[g][0] = g_wx[l][n][0];
      wxc[g][1] = g_wx[l][n][1];
      wxc[g][2] = g_wx[l][n][2];
    }
  }
  float cst[2][4] = {};

  __shared__ float red[2][2][64][40];     // [jts][kh][lane][2mt*4g*4]
  __shared__ int s_ab[4];

#define GL1(B, J, OFF) if ((J) < nk) \
  asm volatile("global_load_dwordx4 %0, %1, off offset:" OFF " sc0 sc1" \
               : "=v"(A[B][J]) : "v"(rpc))
#define LOADNK(B, P) { const u16* rpc = (P); \
  GL1(B,0,"0"); GL1(B,1,"64"); GL1(B,2,"128"); GL1(B,3,"192"); GL1(B,4,"256"); \
  GL1(B,5,"320"); GL1(B,6,"384"); GL1(B,7,"448"); GL1(B,8,"512"); GL1(B,9,"576"); \
  GL1(B,10,"640"); GL1(B,11,"704"); GL1(B,12,"768"); }
#define WV(N) asm volatile("s_waitcnt vmcnt(" #N ")" ::: "memory")

  for (int t = 0; t < TT; ++t) {
    // ---------- x-gate precompute for owned mtiles (overlaps wait) ----------
    float xg[2][4][4];
    if (!idle) {
#pragma unroll
      for (int am2 = 0; am2 < 2; ++am2)
#pragma unroll
        for (int r = 0; r < 4; ++r) {
          int row = (am0 + am2) * 16 + kg * 4 + r;
          const float* xp = X + ((long)row * TT + t) * 3;
          float x0 = xp[0], x1 = xp[1], x2 = xp[2];
#pragma unroll
          for (int g = 0; g < 4; ++g)
            xg[am2][g][r] = bsum[g] + wxc[g][0] * x0 + wxc[g][1] * x1 + wxc[g][2] * x2;
        }
    }

    // ---------- per-wave wait on exactly the needed flag line ----------
    int ab = 0;
    if (!idle) {
      if (selfw) { if (t > 0) ab = wait_line(&g_fl[l][0], t, w2); }
      else       { ab = wait_line(&g_fl[l - 1][0], t + 1, -1); }
    }
    if (lane == 0) s_ab[wv] = ab;

    // ---------- A 2-deep pipelined MFMA over 4 mtiles ----------
    f32x4 acc[4][4] = {};
    const bool doA = (!idle) && (!ab) && (selfw ? (t > 0) : true);
    if (doA) {
      const u16* rp[4];
#pragma unroll
      for (int am = 0; am < 4; ++am)
        rp[am] = selfw
          ? &g_h[l][(t - 1) & 1][am * 16 + brow][ksA0 * 32 + kg * 8]
          : &g_outs[(long)(am * 16 + brow) * TT + t][(l - 1) * SEG + kg * 8];
      bf16x8 A[2][13];
      LOADNK(0, rp[0]);
#pragma unroll
      for (int am = 0; am < 4; ++am) {
        if (am < 3) LOADNK((am + 1) & 1, rp[am + 1]);
        if (am < 3) { if (nk == 13) WV(13); else if (nk == 7) WV(7); else WV(6); }
        else WV(0);
        __builtin_amdgcn_sched_barrier(0);
#pragma unroll
        for (int j = 0; j < 13; ++j)
          if (j < nk)
#pragma unroll
            for (int g = 0; g < 4; ++g)
              acc[am][g] = __builtin_amdgcn_mfma_f32_16x16x32_bf16(
                  A[am & 1][j], Bf[g][j], acc[am][g], 0, 0, 0);
      }
    }

    // ---------- split-K join: deposit NON-owned mtiles, read peer's ----------
    if (!idle) {
#pragma unroll
      for (int am2 = 0; am2 < 2; ++am2) {
        int amW = (kh ^ 1) * 2 + am2;
#pragma unroll
        for (int g = 0; g < 4; ++g)
          *(f32x4*)&red[jts][kh][lane][(am2 * 4 + g) * 4] = acc[amW][g];
      }
    }
    __syncthreads();
    if (s_ab[0] | s_ab[1] | s_ab[2] | s_ab[3]) return;

    // ---------- epilogue: gates -> c,h for owned mtiles ----------
    if (!idle) {
#pragma unroll
      for (int am2 = 0; am2 < 2; ++am2) {
        f32x4 gacc[4];
#pragma unroll
        for (int g = 0; g < 4; ++g)
          gacc[g] = acc[am0 + am2][g]
                  + *(const f32x4*)&red[jts][kh ^ 1][lane][(am2 * 4 + g) * 4];
#pragma unroll
        for (int r = 0; r < 4; ++r) {
          int row = (am0 + am2) * 16 + kg * 4 + r;
          float gate[4];
#pragma unroll
          for (int g = 0; g < 4; ++g) gate[g] = gacc[g][r] + xg[am2][g][r];
          float ig = sigm(gate[0]), fg = sigm(gate[1]);
          float gg = tanh_(gate[2]), og = sigm(gate[3]);
          float c = fg * cst[am2][r] + ig * gg;
          cst[am2][r] = c;
          unsigned hb = (unsigned)f2b(og * tanh_(c));
          st16_s(&g_h[l][t & 1][row][jh], hb);
          st16_s(&g_outs[(long)row * TT + t][l * SEG + jh], hb);
        }
      }
    }

    // ---------- drain + publish (one flag store per WG) ----------
    __syncthreads();   // drains vmcnt/lgkmcnt for all waves
    if (tid == 0) st32_s(&g_fl[l][w2], t + 1);
  }
#undef GL1
#undef LOADNK
#undef WV
}

// ---------------- final projection: [65536,1248] x [1248,128] ----------------
__global__ __launch_bounds__(256) void k_final(float* __restrict__ out) {
  int mt   = blockIdx.x * 4 + (threadIdx.x >> 6);
  int lane = threadIdx.x & 63;
  int arow = mt * 16 + (lane & 15);
  int kchunk = (lane >> 4) * 8;
  f32x4 acc[8] = {};
  for (int ks = 0; ks < KSL; ++ks) {
    bf16x8 a = *(const bf16x8*)&g_outs[arow][ks * 32 + kchunk];
#pragma unroll
    for (int nt = 0; nt < 8; ++nt) {
      bf16x8 b = *(const bf16x8*)&g_pkl[nt][ks][lane * 8];
      acc[nt] = __builtin_amdgcn_mfma_f32_16x16x32_bf16(a, b, acc[nt], 0, 0, 0);
    }
  }
#pragma unroll
  for (int nt = 0; nt < 8; ++nt) {
    int o = nt * 16 + (lane & 15);
    if (o >= NOUT) continue;
#pragma unroll
    for (int r = 0; r < 4; ++r) {
      int m = mt * 16 + (lane >> 4) * 4 + r;
      out[(long)m * NOUT + o] = acc[nt][r] + g_bl[o];
    }
  }
}

// ---------------- launch ----------------
extern "C" void kernel_launch(void* const* d_in, const int* in_sizes, int n_in,
                              void* d_out, int out_size, void* d_ws, size_t ws_size,
                              hipStream_t stream) {
  const float* X    = (const float*)d_in[0];
  const float* Wih0 = (const float*)d_in[1];
  const float* Whh0 = (const float*)d_in[2];
  const float* bih0 = (const float*)d_in[3];
  const float* bhh0 = (const float*)d_in[4];
  const float* Wih1 = (const float*)d_in[5];
  const float* Whh1 = (const float*)d_in[6];
  const float* bih1 = (const float*)d_in[7];
  const float* bhh1 = (const float*)d_in[8];
  const float* Wih2 = (const float*)d_in[9];
  const float* Whh2 = (const float*)d_in[10];
  const float* bih2 = (const float*)d_in[11];
  const float* bhh2 = (const float*)d_in[12];
  const float* Wl   = (const float*)d_in[13];
  const float* bl   = (const float*)d_in[14];

  k_zero<<<(BB * TT * 24 + 255) / 256, 256, 0, stream>>>();
  k_pack_rec<<<(100 * KS0  * 512 + 255) / 256, 256, 0, stream>>>(nullptr, Whh0, 0, KS0, 3);
  k_pack_rec<<<(100 * KS12 * 512 + 255) / 256, 256, 0, stream>>>(Wih1, Whh1, 1, KS12, 403);
  k_pack_rec<<<(100 * KS12 * 512 + 255) / 256, 256, 0, stream>>>(Wih2, Whh2, 2, KS12, 403);
  k_pack_wl<<<(8 * KSL * 512 + 255) / 256, 256, 0, stream>>>(Wl, bl);
  k_pack_misc<<<(3 * G4 + 255) / 256, 256, 0, stream>>>(Wih0, bih0, bhh0,
                                                        Wih1, bih1, bhh1,
                                                        Wih2, bih2, bhh2);
  k_lstm<<<3 * NWG, 256, 0, stream>>>(X);
  k_final<<<1024, 256, 0, stream>>>((float*)d_out);
}

// Round 7
// 4477.372 us; speedup vs baseline: 3.7531x; 3.7531x over previous
//
#include <hip/hip_runtime.h>
#include <hip/hip_bf16.h>

// ---------------- sizes ----------------
#define H    400
#define SEG  416          // per-layer feature segment, padded to 13*32
#define G4   1600
#define TT   1024
#define BB   64
#define NOUT 121
#define KS0  13
#define KS12 26
#define FPAD 1248         // 3*SEG
#define KSL  39
#define NG   25           // producer slots per flag line

typedef __attribute__((ext_vector_type(8))) short bf16x8;
typedef __attribute__((ext_vector_type(4))) float f32x4;
typedef unsigned short u16;

// ---------------- persistent device state ----------------
__device__ __align__(16) u16   g_outs[BB * TT][FPAD];   // inter-layer + final GEMM A
__device__ __align__(16) u16   g_h[3][2][BB][SEG];      // self h, parity double buffer
__device__ __align__(16) u16   g_pk0[100][KS0][512];
__device__ __align__(16) u16   g_pk1[100][KS12][512];
__device__ __align__(16) u16   g_pk2[100][KS12][512];
__device__ __align__(16) u16   g_pkl[8][KSL][512];
__device__ float g_bsum[3][G4];
__device__ float g_wx[3][G4][3];
__device__ float g_bl[128];
// self-chain flags (guard g_h): g_f[l][mtile][jt] = t+1 when that wave's h(t) drained
__device__ __align__(128) int g_f[3][4][32];
// inter-layer flags (guard g_outs): g_fo[l][mtile][jt]
__device__ __align__(128) int g_fo[2][4][32];
__device__ int   g_abort;

// ---------------- helpers ----------------
__device__ inline u16 f2b(float f) {
  union { float f; unsigned u; } v; v.f = f;
  unsigned r = v.u + 0x7FFF + ((v.u >> 16) & 1);
  return (u16)(r >> 16);
}
__device__ inline float sigm(float x) { return 1.f / (1.f + __expf(-x)); }
__device__ inline float tanh_(float x) { return 2.f * sigm(2.f * x) - 1.f; }

// verified cross-XCD coherent accessors: sc0 sc1 only
__device__ inline void st16_s(u16* p, unsigned v) {
  asm volatile("global_store_short %0, %1, off sc0 sc1" :: "v"(p), "v"(v) : "memory");
}
__device__ inline void st32_s(int* p, int v) {
  asm volatile("global_store_dword %0, %1, off sc0 sc1" :: "v"(p), "v"(v) : "memory");
}
__device__ inline int poll_s(const int* p) {
  int v;
  asm volatile("global_load_dword %0, %1, off sc0 sc1\n\ts_waitcnt vmcnt(0)"
               : "=v"(v) : "v"(p) : "memory");
  return v;
}
// wave-cooperative wait: all NG slots >= tv (slot==skip exempt). 1 = abort.
// SLEEP=1 adds s_sleep backoff (for slack-tolerant inter-layer waits).
template <int SLEEP>
__device__ inline int wait_line(const int* line, int tv, int skip) {
  const int slot = threadIdx.x & 31;
  const int* p = line + slot;
  const bool act = (slot < NG) && (slot != skip);
  long n = 0;
  for (;;) {
    int v = poll_s(p);
    if (__all((!act) || (v >= tv))) return 0;
    if (SLEEP) __builtin_amdgcn_s_sleep(2);
    if ((++n & 255) == 0) {
      if (poll_s(&g_abort)) return 1;
      if (n > (1L << 21)) { st32_s(&g_abort, 1); return 1; }
    }
  }
}

// ---------------- setup kernels ----------------
__global__ void k_zero() {
  int i = blockIdx.x * blockDim.x + threadIdx.x;
  if (i == 0) g_abort = 0;
  if (i < 3 * 4 * 32) (&g_f[0][0][0])[i] = 0;
  if (i < 2 * 4 * 32) (&g_fo[0][0][0])[i] = 0;
  if (i < 3 * 2 * BB * SEG / 2) ((unsigned*)g_h)[i] = 0u;
  if (i < BB * TT * 24) {                  // zero pad columns of g_outs
    int r = i / 24, j = i % 24;
    int seg = j >> 3, w = j & 7;
    *(unsigned*)&g_outs[r][seg * SEG + 400 + w * 2] = 0u;
  }
}

__global__ void k_pack_rec(const float* Wih, const float* Whh, int layer,
                           int ksteps, int kin) {
  int i = blockIdx.x * blockDim.x + threadIdx.x;
  int total = 100 * ksteps * 512;
  if (i >= total) return;
  int j = i & 7, lane = (i >> 3) & 63;
  int ks = (i >> 9) % ksteps, nt = (i >> 9) / ksteps;
  int g = nt / 25, jt = nt % 25;
  int n  = g * 400 + jt * 16 + (lane & 15);
  int kk = (lane >> 4) * 8 + j;
  float v = 0.f;
  if (layer == 0) {
    int k = ks * 32 + kk;
    if (k < H) v = Whh[n * H + k];
  } else {
    if (ks < KS0) { int k = ks * 32 + kk;         if (k < H) v = Wih[n * kin + 3 + k]; }
    else          { int k = (ks - KS0) * 32 + kk; if (k < H) v = Whh[n * H + k]; }
  }
  u16* dst = (layer == 0) ? &g_pk0[0][0][0] : (layer == 1 ? &g_pk1[0][0][0] : &g_pk2[0][0][0]);
  dst[i] = f2b(v);
}

__global__ void k_pack_wl(const float* Wl, const float* bl) {
  int i = blockIdx.x * blockDim.x + threadIdx.x;
  if (i < 128) g_bl[i] = (i < NOUT) ? bl[i] : 0.f;
  int total = 8 * KSL * 512;
  if (i >= total) return;
  int j = i & 7, lane = (i >> 3) & 63;
  int ks = (i >> 9) % KSL, nt = (i >> 9) / KSL;
  int n = nt * 16 + (lane & 15);
  int k = ks * 32 + (lane >> 4) * 8 + j;
  int seg = k / SEG, jj = k - seg * SEG;
  float v = 0.f;
  if (n < NOUT && jj < 400) v = Wl[n * 1200 + seg * 400 + jj];
  (&g_pkl[0][0][0])[i] = f2b(v);
}

__global__ void k_pack_misc(const float* Wih0, const float* bih0, const float* bhh0,
                            const float* Wih1, const float* bih1, const float* bhh1,
                            const float* Wih2, const float* bih2, const float* bhh2) {
  int i = blockIdx.x * blockDim.x + threadIdx.x;
  if (i >= 3 * G4) return;
  int l = i / G4, n = i % G4;
  const float* bi = l == 0 ? bih0 : (l == 1 ? bih1 : bih2);
  const float* bh = l == 0 ? bhh0 : (l == 1 ? bhh1 : bhh2);
  const float* wi = l == 0 ? Wih0 : (l == 1 ? Wih1 : Wih2);
  int kin = l == 0 ? 3 : 403;
  g_bsum[l][n] = bi[n] + bh[n];
  for (int c = 0; c < 3; ++c) g_wx[l][n][c] = wi[n * kin + c];
}

// ---------------- persistent LSTM, short self-loop ----------------
// 125 WGs: l0 = 25 WGs (4 autonomous waves, one mtile each, NO barriers);
// l1/l2 = 50 WGs each (2 pairs x {kh=0 inter-wave, kh=1 self-wave}, one
// barrier/step via parity-double-buffered LDS join; epilogue duplicated).
// kh=1 critical wave: g_h stores only -> own drain -> own g_f slot.
// kh=0 slack wave: g_outs stores -> g_fo slot (sleep-backoff polling).
__global__ __launch_bounds__(256, 1) void k_lstm(const float* __restrict__ X) {
  const int wg = blockIdx.x;
  int l, w2;
  if (wg < 25)      { l = 0; w2 = wg; }
  else if (wg < 75) { l = 1; w2 = wg - 25; }
  else              { l = 2; w2 = wg - 75; }

  const int tid = threadIdx.x;
  const int lane = tid & 63;
  const int wv = tid >> 6;
  const int brow = lane & 15;
  const int kg = lane >> 4;

  int jt, mtile, kh, pair;
  if (l == 0) { jt = w2; mtile = wv; kh = 1; pair = 0; }
  else { int bg = w2 & 1; jt = w2 >> 1; kh = wv & 1; pair = wv >> 1; mtile = bg * 2 + pair; }
  const int jh = jt * 16 + brow;

  const u16* pk = (l == 0) ? &g_pk0[0][0][0] : (l == 1 ? &g_pk1[0][0][0] : &g_pk2[0][0][0]);
  const int nks = (l == 0) ? KS0 : KS12;
  const int wks0 = (l == 0) ? 0 : kh * 13;

  bf16x8 Bf[4][13];
#pragma unroll
  for (int g = 0; g < 4; ++g)
#pragma unroll
    for (int j = 0; j < 13; ++j)
      Bf[g][j] = *(const bf16x8*)&pk[(((g * 25 + jt) * nks + wks0 + j) * 64 + lane) * 8];

  float bsum[4], wxc[4][3];
#pragma unroll
  for (int g = 0; g < 4; ++g) {
    int n = g * 400 + jh;
    bsum[g] = g_bsum[l][n];
    wxc[g][0] = g_wx[l][n][0];
    wxc[g][1] = g_wx[l][n][1];
    wxc[g][2] = g_wx[l][n][2];
  }
  float cst[4] = {0.f, 0.f, 0.f, 0.f};

  __shared__ float red[2][2][2][64][20];   // [pair][parity][kh][lane][16+pad]
  __shared__ int s_ab[2][4];

#define GLS(i, OFF) asm volatile("global_load_dwordx4 %0, %1, off offset:" OFF " sc0 sc1" \
                                 : "=v"(A[i]) : "v"(rowp))
#define GLS_ALL GLS(0,"0");GLS(1,"64");GLS(2,"128");GLS(3,"192");GLS(4,"256");GLS(5,"320"); \
                GLS(6,"384");GLS(7,"448");GLS(8,"512");GLS(9,"576");GLS(10,"640");          \
                GLS(11,"704");GLS(12,"768")
#define XGATE(xg) { \
  _Pragma("unroll") \
  for (int r = 0; r < 4; ++r) { \
    int row = mtile * 16 + kg * 4 + r; \
    const float* xp = X + ((long)row * TT + t) * 3; \
    float x0 = xp[0], x1 = xp[1], x2 = xp[2]; \
    _Pragma("unroll") \
    for (int g = 0; g < 4; ++g) \
      xg[g][r] = bsum[g] + wxc[g][0] * x0 + wxc[g][1] * x1 + wxc[g][2] * x2; \
  } }
#define MFMA_ALL { asm volatile("s_waitcnt vmcnt(0)" ::: "memory"); \
  __builtin_amdgcn_sched_barrier(0); \
  _Pragma("unroll") \
  for (int j = 0; j < 13; ++j) \
    _Pragma("unroll") \
    for (int g = 0; g < 4; ++g) \
      acc[g] = __builtin_amdgcn_mfma_f32_16x16x32_bf16(A[j], Bf[g][j], acc[g], 0, 0, 0); }

  if (l == 0) {
    // ===== layer 0: fully autonomous waves, zero barriers =====
    for (int t = 0; t < TT; ++t) {
      float xg[4][4];
      XGATE(xg);
      f32x4 acc[4] = {};
      if (t > 0) {
        if (wait_line<0>(&g_f[0][mtile][0], t, jt)) return;
        const u16* rowp = &g_h[0][(t - 1) & 1][mtile * 16 + brow][kg * 8];
        bf16x8 A[13];
        GLS_ALL;
        MFMA_ALL;
      }
      unsigned hb[4];
#pragma unroll
      for (int r = 0; r < 4; ++r) {
        float gate[4];
#pragma unroll
        for (int g = 0; g < 4; ++g) gate[g] = acc[g][r] + xg[g][r];
        float ig = sigm(gate[0]), fg = sigm(gate[1]);
        float gg = tanh_(gate[2]), og = sigm(gate[3]);
        float c = fg * cst[r] + ig * gg;
        cst[r] = c;
        hb[r] = (unsigned)f2b(og * tanh_(c));
        st16_s(&g_h[0][t & 1][mtile * 16 + kg * 4 + r][jh], hb[r]);
      }
      asm volatile("s_waitcnt vmcnt(0)" ::: "memory");
      if (lane == 0) st32_s(&g_f[0][mtile][jt], t + 1);       // self-chain published
#pragma unroll
      for (int r = 0; r < 4; ++r)
        st16_s(&g_outs[(long)(mtile * 16 + kg * 4 + r) * TT + t][jh], hb[r]);
      asm volatile("s_waitcnt vmcnt(0)" ::: "memory");
      if (lane == 0) st32_s(&g_fo[0][mtile][jt], t + 1);      // inter published
    }
    return;
  }

  // ===== layers 1/2: pairs {kh=0 inter-wave, kh=1 self-wave}, 1 barrier/step =====
  for (int t = 0; t < TT; ++t) {
    float xg[4][4];
    XGATE(xg);

    int ab = 0;
    const bool doA = kh ? (t > 0) : true;
    if (kh) { if (t > 0) ab = wait_line<0>(&g_f[l][mtile][0], t, jt); }
    else    { ab = wait_line<1>(&g_fo[l - 1][mtile][0], t + 1, -1); }
    if (lane == 0) s_ab[t & 1][wv] = ab;

    f32x4 acc[4] = {};
    if (doA && !ab) {
      const u16* rowp = kh
        ? &g_h[l][(t - 1) & 1][mtile * 16 + brow][kg * 8]
        : &g_outs[(long)(mtile * 16 + brow) * TT + t][(l - 1) * SEG + kg * 8];
      bf16x8 A[13];
      GLS_ALL;
      MFMA_ALL;
    }

    // deposit own partial; single barrier; join with peer's
#pragma unroll
    for (int g = 0; g < 4; ++g)
      *(f32x4*)&red[pair][t & 1][kh][lane][g * 4] = acc[g];
    __syncthreads();
    if (s_ab[t & 1][0] | s_ab[t & 1][1] | s_ab[t & 1][2] | s_ab[t & 1][3]) return;
    f32x4 gacc[4];
#pragma unroll
    for (int g = 0; g < 4; ++g)
      gacc[g] = acc[g] + *(const f32x4*)&red[pair][t & 1][kh ^ 1][lane][g * 4];

    // epilogue duplicated on both waves (identical fp -> identical bits)
    unsigned hb[4];
#pragma unroll
    for (int r = 0; r < 4; ++r) {
      float gate[4];
#pragma unroll
      for (int g = 0; g < 4; ++g) gate[g] = gacc[g][r] + xg[g][r];
      float ig = sigm(gate[0]), fg = sigm(gate[1]);
      float gg = tanh_(gate[2]), og = sigm(gate[3]);
      float c = fg * cst[r] + ig * gg;
      cst[r] = c;
      hb[r] = (unsigned)f2b(og * tanh_(c));
    }

    if (kh) {
      // critical wave: h only, own drain, own flag slot
#pragma unroll
      for (int r = 0; r < 4; ++r)
        st16_s(&g_h[l][t & 1][mtile * 16 + kg * 4 + r][jh], hb[r]);
      asm volatile("s_waitcnt vmcnt(0)" ::: "memory");
      if (lane == 0) st32_s(&g_f[l][mtile][jt], t + 1);
    } else {
      // slack wave: g_outs + inter flag (l==2 has no consumer until k_final)
#pragma unroll
      for (int r = 0; r < 4; ++r)
        st16_s(&g_outs[(long)(mtile * 16 + kg * 4 + r) * TT + t][l * SEG + jh], hb[r]);
      if (l == 1) {
        asm volatile("s_waitcnt vmcnt(0)" ::: "memory");
        if (lane == 0) st32_s(&g_fo[1][mtile][jt], t + 1);
      }
    }
  }
#undef GLS
#undef GLS_ALL
#undef XGATE
#undef MFMA_ALL
}

// ---------------- final projection: [65536,1248] x [1248,128] ----------------
__global__ __launch_bounds__(256) void k_final(float* __restrict__ out) {
  int mt   = blockIdx.x * 4 + (threadIdx.x >> 6);
  int lane = threadIdx.x & 63;
  int arow = mt * 16 + (lane & 15);
  int kchunk = (lane >> 4) * 8;
  f32x4 acc[8] = {};
  for (int ks = 0; ks < KSL; ++ks) {
    bf16x8 a = *(const bf16x8*)&g_outs[arow][ks * 32 + kchunk];
#pragma unroll
    for (int nt = 0; nt < 8; ++nt) {
      bf16x8 b = *(const bf16x8*)&g_pkl[nt][ks][lane * 8];
      acc[nt] = __builtin_amdgcn_mfma_f32_16x16x32_bf16(a, b, acc[nt], 0, 0, 0);
    }
  }
#pragma unroll
  for (int nt = 0; nt < 8; ++nt) {
    int o = nt * 16 + (lane & 15);
    if (o >= NOUT) continue;
#pragma unroll
    for (int r = 0; r < 4; ++r) {
      int m = mt * 16 + (lane >> 4) * 4 + r;
      out[(long)m * NOUT + o] = acc[nt][r] + g_bl[o];
    }
  }
}

// ---------------- launch ----------------
extern "C" void kernel_launch(void* const* d_in, const int* in_sizes, int n_in,
                              void* d_out, int out_size, void* d_ws, size_t ws_size,
                              hipStream_t stream) {
  const float* X    = (const float*)d_in[0];
  const float* Wih0 = (const float*)d_in[1];
  const float* Whh0 = (const float*)d_in[2];
  const float* bih0 = (const float*)d_in[3];
  const float* bhh0 = (const float*)d_in[4];
  const float* Wih1 = (const float*)d_in[5];
  const float* Whh1 = (const float*)d_in[6];
  const float* bih1 = (const float*)d_in[7];
  const float* bhh1 = (const float*)d_in[8];
  const float* Wih2 = (const float*)d_in[9];
  const float* Whh2 = (const float*)d_in[10];
  const float* bih2 = (const float*)d_in[11];
  const float* bhh2 = (const float*)d_in[12];
  const float* Wl   = (const float*)d_in[13];
  const float* bl   = (const float*)d_in[14];

  k_zero<<<(BB * TT * 24 + 255) / 256, 256, 0, stream>>>();
  k_pack_rec<<<(100 * KS0  * 512 + 255) / 256, 256, 0, stream>>>(nullptr, Whh0, 0, KS0, 3);
  k_pack_rec<<<(100 * KS12 * 512 + 255) / 256, 256, 0, stream>>>(Wih1, Whh1, 1, KS12, 403);
  k_pack_rec<<<(100 * KS12 * 512 + 255) / 256, 256, 0, stream>>>(Wih2, Whh2, 2, KS12, 403);
  k_pack_wl<<<(8 * KSL * 512 + 255) / 256, 256, 0, stream>>>(Wl, bl);
  k_pack_misc<<<(3 * G4 + 255) / 256, 256, 0, stream>>>(Wih0, bih0, bhh0,
                                                        Wih1, bih1, bhh1,
                                                        Wih2, bih2, bhh2);
  k_lstm<<<125, 256, 0, stream>>>(X);
  k_final<<<1024, 256, 0, stream>>>((float*)d_out);
}